// Round 7
// baseline (203.385 us; speedup 1.0000x reference)
//
#include <hip/hip_runtime.h>
#include <math.h>

#define PROJ 8192
#define CDIM 512
#define HWPOS 196
#define NBATCH 32
#define NSLAB 7             // K padded 196 -> 224 = 7 slabs of 32
#define NSEG 16             // 4 diag tiles + 6 pairs x {fwd, mirror}; 16384 entries each

typedef __attribute__((ext_vector_type(8))) short   short8;
typedef __attribute__((ext_vector_type(4))) float   f32x4;

__device__ __forceinline__ unsigned short f2bf(float f) {
    unsigned u = __float_as_uint(f);
    u += 0x7fff + ((u >> 16) & 1);          // round-to-nearest-even
    return (unsigned short)(u >> 16);
}
__device__ __forceinline__ float bf2f(unsigned short h) {
    return __uint_as_float(((unsigned)h) << 16);
}

// Segment decode (r4-verified packs). seg 0..3: diag (t,t) fwd; 4..9: pairs
// (0,1)(0,2)(0,3)(1,2)(1,3)(2,3) fwd; 10..15: same pairs, mirror orientation.
#define BI_PACK 0x2110002110003210ULL
#define BJ_PACK 0x3323213323213210ULL

// Entry e in [0,16384): r=e>>7, c=e&127 of tile (bi,bj).
// fwd:    bin = h1[bi*128+r] + h2[bj*128+c], sign = s1[..r]*s2[..c]
// mirror: bin = h1[bj*128+c] + h2[bi*128+r], sign = s1[..c]*s2[..r]
// (exactly the two verified r4 scatter lines). Both read tile[r][c].
__device__ __forceinline__ void seg_entry(int seg, int e,
    const int* __restrict__ h1, const float* __restrict__ s1,
    const int* __restrict__ h2, const float* __restrict__ s2,
    int& bin, int& sg)
{
    const int bi = (int)((BI_PACK >> (seg * 4)) & 15);
    const int bj = (int)((BJ_PACK >> (seg * 4)) & 15);
    const int r = e >> 7, c = e & 127;
    int gi, gj;
    if (seg < 10) { gi = bi * 128 + r; gj = bj * 128 + c; }
    else          { gi = bj * 128 + c; gj = bi * 128 + r; }
    bin = (h1[gi] + h2[gj]) & (PROJ - 1);
    sg  = (int)((__float_as_uint(s1[gi]) ^ __float_as_uint(s2[gj])) >> 31); // s=+-1
}

// ---------------------------------------------------------------------------
// Kernel 1: extract (h, s) from the dense sketch matrices. (r0 verbatim)
// ---------------------------------------------------------------------------
__global__ __launch_bounds__(256) void extract_kernel(
    const float* __restrict__ M1, const float* __restrict__ M2,
    int* __restrict__ h1, float* __restrict__ s1,
    int* __restrict__ h2, float* __restrict__ s2)
{
    const int row = blockIdx.x;
    const float* M = blockIdx.y ? M2 : M1;
    int*   h = blockIdx.y ? h2 : h1;
    float* s = blockIdx.y ? s2 : s1;
    const float* mrow = M + (size_t)row * PROJ;

    for (int i = threadIdx.x * 4; i < PROJ; i += 256 * 4) {
        float4 v = *(const float4*)(mrow + i);
        if (v.x != 0.0f) { h[row] = i + 0; s[row] = v.x; }
        if (v.y != 0.0f) { h[row] = i + 1; s[row] = v.y; }
        if (v.z != 0.0f) { h[row] = i + 2; s[row] = v.z; }
        if (v.w != 0.0f) { h[row] = i + 3; s[row] = v.w; }
    }
}

// ---------------------------------------------------------------------------
// Kernel 2: combo — blocks 0..223 run prep (r0-verbatim body), blocks
// 224..287 run the CSR histogram (per-block LDS hist, no contention).
// Branch is blockIdx-uniform so the intra-branch __syncthreads are legal.
// ---------------------------------------------------------------------------
__global__ __launch_bounds__(256) void combo_kernel(
    const float* __restrict__ x,
    unsigned short* __restrict__ XThi, unsigned short* __restrict__ XTlo,
    const int* __restrict__ h1, const float* __restrict__ s1,
    const int* __restrict__ h2, const float* __restrict__ s2,
    unsigned* __restrict__ bh)
{
    __shared__ __align__(16) char smem[32 * 513 * 4];   // union: prep xt / hist lh
    const int tid = threadIdx.x;

    if (blockIdx.x < 224) {
        // ---- prep: split fp32 x into bf16 hi/lo, fragment order (r0) ----
        float (*xt)[513] = (float(*)[513])smem;
        const int bat = blockIdx.x >> 3;          // 0..27? no: 224 = 7*32
        const int ks  = blockIdx.x % NSLAB;
        const int bt  = blockIdx.x / NSLAB;       // 0..31
        (void)bat;
        const float* xb = x + (size_t)bt * HWPOS * CDIM;
        const int k0 = ks * 32;
#pragma unroll
        for (int i = 0; i < 16; ++i) {
            const int idx = i * 1024 + tid * 4;
            const int kr  = idx >> 9;
            const int c   = idx & 511;
            float4 v = make_float4(0.f, 0.f, 0.f, 0.f);
            if (k0 + kr < HWPOS) v = *(const float4*)(xb + (size_t)(k0 + kr) * CDIM + c);
            xt[kr][c+0] = v.x; xt[kr][c+1] = v.y; xt[kr][c+2] = v.z; xt[kr][c+3] = v.w;
        }
        __syncthreads();

        unsigned short* ohi = XThi + ((size_t)bt * NSLAB + ks) * 16384;
        unsigned short* olo = XTlo + ((size_t)bt * NSLAB + ks) * 16384;
#pragma unroll
        for (int i = 0; i < 8; ++i) {
            const int ch   = i * 256 + tid;
            const int c16  = ch & 15;
            const int quad = (ch >> 4) & 3;
            const int cgrp = ch >> 6;
            const int c    = cgrp * 16 + c16;
            short8 vh, vl;
#pragma unroll
            for (int j = 0; j < 8; ++j) {
                float f = xt[quad * 8 + j][c];
                unsigned short h = f2bf(f);
                vh[j] = (short)h;
                vl[j] = (short)f2bf(f - bf2f(h));
            }
            *(short8*)(ohi + ch * 8) = vh;
            *(short8*)(olo + ch * 8) = vl;
        }
    } else {
        // ---- histogram: block handles quarter q of segment seg ----
        unsigned* lh = (unsigned*)smem;
        const int blk = blockIdx.x - 224;         // 0..63
        const int seg = blk >> 2, q = blk & 3;
        for (int i = tid; i < PROJ; i += 256) lh[i] = 0u;
        __syncthreads();
#pragma unroll
        for (int k = 0; k < 16; ++k) {
            const int e = q * 4096 + k * 256 + tid;
            int bin, sg;
            seg_entry(seg, e, h1, s1, h2, s2, bin, sg);
            atomicAdd(&lh[bin], 1u);
        }
        __syncthreads();
        unsigned* dst = bh + (size_t)blk * PROJ;
        for (int i = tid; i < PROJ; i += 256) dst[i] = lh[i];
    }
}

// ---------------------------------------------------------------------------
// Kernel 3: scan — per segment: bin totals, exclusive prefix over 8192 bins,
// write binbase[seg][b]; rewrite bh in place as ABSOLUTE per-block bases.
// ---------------------------------------------------------------------------
__global__ __launch_bounds__(256) void scan_kernel(
    unsigned* __restrict__ bh, unsigned* __restrict__ binbase)
{
    const int seg = blockIdx.x;                   // 0..15
    const int tid = threadIdx.x;
    __shared__ unsigned sc[256];
    __shared__ unsigned carry;
    if (tid == 0) carry = 0u;
    __syncthreads();

    unsigned* b0 = bh + (size_t)(seg * 4 + 0) * PROJ;
    unsigned* b1 = bh + (size_t)(seg * 4 + 1) * PROJ;
    unsigned* b2 = bh + (size_t)(seg * 4 + 2) * PROJ;
    unsigned* b3 = bh + (size_t)(seg * 4 + 3) * PROJ;

    for (int k = 0; k < 32; ++k) {
        const int b = k * 256 + tid;
        const unsigned q0 = b0[b], q1 = b1[b], q2 = b2[b], q3 = b3[b];
        const unsigned tot = q0 + q1 + q2 + q3;
        sc[tid] = tot;
        __syncthreads();
        for (int off = 1; off < 256; off <<= 1) { // Hillis-Steele inclusive
            unsigned t = (tid >= off) ? sc[tid - off] : 0u;
            __syncthreads();
            sc[tid] += t;
            __syncthreads();
        }
        const unsigned rc   = carry;              // prev-chunk carry (synced)
        const unsigned incl = sc[tid];
        const unsigned base = rc + incl - tot;    // exclusive prefix
        binbase[(size_t)seg * 8193 + b] = base;
        b0[b] = base;
        b1[b] = base + q0;
        b2[b] = base + q0 + q1;
        b3[b] = base + q0 + q1 + q2;
        __syncthreads();
        if (tid == 255) carry = rc + incl;
        __syncthreads();
    }
    if (tid == 0) binbase[(size_t)seg * 8193 + 8192] = carry;   // = 16384
}

// ---------------------------------------------------------------------------
// Kernel 4: place — re-enumerate entries, local rank via LDS atomic-return,
// write 16-bit CSR entry (sign<<15 | r<<7 | c) at its sorted position.
// ---------------------------------------------------------------------------
__global__ __launch_bounds__(256) void place_kernel(
    const int* __restrict__ h1, const float* __restrict__ s1,
    const int* __restrict__ h2, const float* __restrict__ s2,
    const unsigned* __restrict__ bh, unsigned short* __restrict__ csr)
{
    const int blk = blockIdx.x;                   // 0..63
    const int seg = blk >> 2, q = blk & 3;
    const int tid = threadIdx.x;
    __shared__ unsigned lr[PROJ];
    for (int i = tid; i < PROJ; i += 256) lr[i] = 0u;
    __syncthreads();
    const unsigned* mybase = bh + (size_t)blk * PROJ;
    unsigned short* cs = csr + (size_t)seg * 16384;
#pragma unroll
    for (int k = 0; k < 16; ++k) {
        const int e = q * 4096 + k * 256 + tid;
        int bin, sg;
        seg_entry(seg, e, h1, s1, h2, s2, bin, sg);
        const unsigned rk = atomicAdd(&lr[bin], 1u);
        cs[mybase[bin] + rk] = (unsigned short)(e | (sg << 15));
    }
}

// ---------------------------------------------------------------------------
// Kernel 5: Gram (r4/r6-VERBATIM double-buffered staging + MFMA) + GATHER.
// 512 WGs (16 segs x 32 batches), LDS 64 KB -> 2 WGs/CU. After MFMA the
// Sbuf LDS is dead; acc is stored there as a 128x128 f32 tile, then each
// thread owns 32 strided bins and gathers its CSR entries with plain
// ds_read (bank-parallel) — zero atomics, plain coalesced page writes.
// ---------------------------------------------------------------------------
__global__ __launch_bounds__(256) void gramgather_kernel(
    const unsigned short* __restrict__ XThi, const unsigned short* __restrict__ XTlo,
    const unsigned* __restrict__ binbase, const unsigned short* __restrict__ csr,
    float* __restrict__ pbins)
{
    const int id  = blockIdx.x;                   // 0..511
    const int sub = id >> 3;                      // 0..63
    const int tp  = sub & 15;                     // segment 0..15
    const int bat = (id & 7) + 8 * (sub >> 4);    // XCD swizzle
    const int bi = (int)((BI_PACK >> (tp * 4)) & 15);
    const int bj = (int)((BJ_PACK >> (tp * 4)) & 15);

    const int tid  = threadIdx.x;
    const int w    = tid >> 6;
    const int lane = tid & 63;
    const int rowq = w >> 1, colq = w & 1;

    __shared__ __align__(16) unsigned short Sbuf[2][4][4096]; // 64 KB dbuf, reused as tile

    const int tile = (w < 2) ? bi : bj;
    const unsigned short* srcbase = ((w & 1) ? XTlo : XThi)
                                  + (size_t)bat * NSLAB * 16384 + (size_t)tile * 4096;

    // issue async prefetch of slab 0 (r4 verbatim)
    {
        const unsigned short* src = srcbase;
        unsigned short* dst = &Sbuf[0][w][0];
#pragma unroll
        for (int i = 0; i < 8; ++i)
            __builtin_amdgcn_global_load_lds(
                (const __attribute__((address_space(1))) void*)(src + i * 512 + lane * 8),
                (__attribute__((address_space(3))) void*)(dst + i * 512), 16, 0, 0);
    }

    f32x4 acc[16];
#pragma unroll
    for (int i = 0; i < 16; ++i) { acc[i][0]=0.f; acc[i][1]=0.f; acc[i][2]=0.f; acc[i][3]=0.f; }

    for (int ks = 0; ks < NSLAB; ++ks) {
        __syncthreads();                 // drains vmcnt -> slab ks resident
        const int buf = ks & 1;

        if (ks + 1 < NSLAB) {            // prefetch next slab into other buffer
            const unsigned short* src = srcbase + (size_t)(ks + 1) * 16384;
            unsigned short* dst = &Sbuf[buf ^ 1][w][0];
#pragma unroll
            for (int i = 0; i < 8; ++i)
                __builtin_amdgcn_global_load_lds(
                    (const __attribute__((address_space(1))) void*)(src + i * 512 + lane * 8),
                    (__attribute__((address_space(3))) void*)(dst + i * 512), 16, 0, 0);
        }

        short8 ah[4], al[4], bh4[4], bl[4];
#pragma unroll
        for (int t = 0; t < 4; ++t) {
            ah[t]  = *(const short8*)&Sbuf[buf][0][(rowq * 4 + t) * 512 + lane * 8];
            al[t]  = *(const short8*)&Sbuf[buf][1][(rowq * 4 + t) * 512 + lane * 8];
            bh4[t] = *(const short8*)&Sbuf[buf][2][(colq * 4 + t) * 512 + lane * 8];
            bl[t]  = *(const short8*)&Sbuf[buf][3][(colq * 4 + t) * 512 + lane * 8];
        }
#pragma unroll
        for (int mt = 0; mt < 4; ++mt)
#pragma unroll
            for (int nt = 0; nt < 4; ++nt) {
                const int idx = mt * 4 + nt;
                acc[idx] = __builtin_amdgcn_mfma_f32_16x16x32_bf16(ah[mt], bh4[nt], acc[idx], 0, 0, 0);
                acc[idx] = __builtin_amdgcn_mfma_f32_16x16x32_bf16(ah[mt], bl[nt],  acc[idx], 0, 0, 0);
                acc[idx] = __builtin_amdgcn_mfma_f32_16x16x32_bf16(al[mt], bh4[nt], acc[idx], 0, 0, 0);
            }
    }

    __syncthreads();                     // all waves done with Sbuf -> reuse as tile
    float* tileL = (float*)Sbuf;         // 16384 f32 = 64 KB exactly
    const int quad = lane >> 4;
#pragma unroll
    for (int mt = 0; mt < 4; ++mt)
#pragma unroll
        for (int reg = 0; reg < 4; ++reg) {
            const int rl = rowq * 64 + mt * 16 + quad * 4 + reg;
#pragma unroll
            for (int nt = 0; nt < 4; ++nt) {
                const int cl = colq * 64 + nt * 16 + (lane & 15);
                tileL[rl * 128 + cl] = acc[mt * 4 + nt][reg];
            }
        }
    __syncthreads();                     // tile visible to all waves

    // ---- gather: thread owns bins {tid + 256k}; CSR sorted by bin ----
    const unsigned* bb = binbase + (size_t)tp * 8193;
    const unsigned short* cs = csr + (size_t)tp * 16384;
    float* page = pbins + ((size_t)bat * NSEG + tp) * PROJ;
#pragma unroll 4
    for (int k = 0; k < 32; ++k) {
        const int b = k * 256 + tid;
        const unsigned s0 = bb[b], e0 = bb[b + 1];
        float a = 0.f;
        for (unsigned p = s0; p < e0; ++p) {
            const unsigned ent = cs[p];
            const float tv = tileL[ent & 0x3FFF];        // r*128+c == ent&0x3FFF
            a += (ent & 0x8000) ? -tv : tv;
        }
        page[b] = a;                    // coalesced across lanes
    }
}

// ---------------------------------------------------------------------------
// Kernel 6: finalize — sum 16 pages, signed sqrt, block-reduce norm, scale.
// (r6 verbatim, NPAGES 8 -> 16)
// ---------------------------------------------------------------------------
__global__ __launch_bounds__(512) void finalize_kernel(
    const float* __restrict__ pbins, float* __restrict__ out)
{
    const int bat = blockIdx.x;
    const int tid = threadIdx.x;
    const float* pb = pbins + (size_t)bat * NSEG * PROJ;

    float4 y0, y1, y2, y3;
    float local = 0.f;

#pragma unroll
    for (int c = 0; c < 4; ++c) {
        const int base = c * 2048 + tid * 4;
        float4 a = make_float4(0.f, 0.f, 0.f, 0.f);
#pragma unroll
        for (int t = 0; t < NSEG; ++t) {
            float4 p = *(const float4*)(pb + (size_t)t * PROJ + base);
            a.x += p.x; a.y += p.y; a.z += p.z; a.w += p.w;
        }
        local += fabsf(a.x) + fabsf(a.y) + fabsf(a.z) + fabsf(a.w);
        float4 sv;
        sv.x = (a.x >= 0.f) ? sqrtf(a.x) : -sqrtf(-a.x);
        sv.y = (a.y >= 0.f) ? sqrtf(a.y) : -sqrtf(-a.y);
        sv.z = (a.z >= 0.f) ? sqrtf(a.z) : -sqrtf(-a.z);
        sv.w = (a.w >= 0.f) ? sqrtf(a.w) : -sqrtf(-a.w);
        if (c == 0) y0 = sv; else if (c == 1) y1 = sv; else if (c == 2) y2 = sv; else y3 = sv;
    }

#pragma unroll
    for (int off = 32; off > 0; off >>= 1) local += __shfl_down(local, off, 64);

    __shared__ float wred[8];
    __shared__ float sinv;
    if ((tid & 63) == 0) wred[tid >> 6] = local;
    __syncthreads();
    if (tid == 0) {
        float t = 0.f;
#pragma unroll
        for (int i = 0; i < 8; ++i) t += wred[i];
        sinv = rsqrtf(fmaxf(t, 1e-10f));
    }
    __syncthreads();
    const float inv = sinv;

    float* ob = out + (size_t)bat * PROJ;
#pragma unroll
    for (int c = 0; c < 4; ++c) {
        float4 sv = (c == 0) ? y0 : (c == 1) ? y1 : (c == 2) ? y2 : y3;
        sv.x *= inv; sv.y *= inv; sv.z *= inv; sv.w *= inv;
        *(float4*)(ob + c * 2048 + tid * 4) = sv;
    }
}

// ---------------------------------------------------------------------------
extern "C" void kernel_launch(void* const* d_in, const int* in_sizes, int n_in,
                              void* d_out, int out_size, void* d_ws, size_t ws_size,
                              hipStream_t stream)
{
    const float* x  = (const float*)d_in[0];   // [32,14,14,512]
    const float* M1 = (const float*)d_in[1];   // [512,8192]
    const float* M2 = (const float*)d_in[2];   // [512,8192]
    float* out = (float*)d_out;                // [32,8192]

    char* ws = (char*)d_ws;
    int*            h1      = (int*)   (ws + 0);
    float*          s1      = (float*) (ws + 2048);
    int*            h2      = (int*)   (ws + 4096);
    float*          s2      = (float*) (ws + 6144);
    unsigned*       binbase = (unsigned*)(ws + 16384);          //   524,352 B
    unsigned short* csr     = (unsigned short*)(ws + 540736);   //   524,288 B
    unsigned short* XThi    = (unsigned short*)(ws + 1065984);  // 7,340,032 B
    unsigned short* XTlo    = (unsigned short*)(ws + 8406016);  // 7,340,032 B
    float*          pbins   = (float*) (ws + 15746048);         // 16,777,216 B
    unsigned*       bh      = (unsigned*)pbins;                 // 2 MB build scratch,
                                                                // dead before pbins written
    // total ws use 32,523,264 B = 31.02 MB (< 31.46 MB proven in round 4)

    extract_kernel<<<dim3(512, 2), 256, 0, stream>>>(M1, M2, h1, s1, h2, s2);
    combo_kernel<<<288, 256, 0, stream>>>(x, XThi, XTlo, h1, s1, h2, s2, bh);
    scan_kernel<<<NSEG, 256, 0, stream>>>(bh, binbase);
    place_kernel<<<64, 256, 0, stream>>>(h1, s1, h2, s2, bh, csr);
    gramgather_kernel<<<NSEG * NBATCH, 256, 0, stream>>>(XThi, XTlo, binbase, csr, pbins);
    finalize_kernel<<<NBATCH, 512, 0, stream>>>(pbins, out);
}

// Round 8
// 179.639 us; speedup vs baseline: 1.1322x; 1.1322x over previous
//
#include <hip/hip_runtime.h>
#include <math.h>

#define PROJ 8192
#define CDIM 512
#define HWPOS 196
#define NBATCH 32
#define NSLAB 7             // K padded 196 -> 224 = 7 slabs of 32
#define NSEG 16             // 4 diag + 6 pairs x {fwd, mirror}; 16384 entries each

typedef __attribute__((ext_vector_type(8))) short   short8;
typedef __attribute__((ext_vector_type(4))) float   f32x4;

__device__ __forceinline__ unsigned short f2bf(float f) {
    unsigned u = __float_as_uint(f);
    u += 0x7fff + ((u >> 16) & 1);          // round-to-nearest-even
    return (unsigned short)(u >> 16);
}
__device__ __forceinline__ float bf2f(unsigned short h) {
    return __uint_as_float(((unsigned)h) << 16);
}

// Segment decode (r4/r7-verified packs). seg 0..3: diag (t,t) fwd; 4..9: pairs
// (0,1)(0,2)(0,3)(1,2)(1,3)(2,3) fwd; 10..15: same pairs, mirror orientation.
#define BI_PACK 0x2110002110003210ULL
#define BJ_PACK 0x3323213323213210ULL

// Entry e in [0,16384): r=e>>7, c=e&127 of tile (bi,bj). (r7-verbatim, passed)
__device__ __forceinline__ void seg_entry(int seg, int e,
    const int* __restrict__ h1, const float* __restrict__ s1,
    const int* __restrict__ h2, const float* __restrict__ s2,
    int& bin, int& sg)
{
    const int bi = (int)((BI_PACK >> (seg * 4)) & 15);
    const int bj = (int)((BJ_PACK >> (seg * 4)) & 15);
    const int r = e >> 7, c = e & 127;
    int gi, gj;
    if (seg < 10) { gi = bi * 128 + r; gj = bj * 128 + c; }
    else          { gi = bj * 128 + c; gj = bi * 128 + r; }
    bin = (h1[gi] + h2[gj]) & (PROJ - 1);
    sg  = (int)((__float_as_uint(s1[gi]) ^ __float_as_uint(s2[gj])) >> 31); // s=+-1
}

// ---------------------------------------------------------------------------
// Kernel 1: extract (h, s) from the dense sketch matrices. (r0 verbatim)
// ---------------------------------------------------------------------------
__global__ __launch_bounds__(256) void extract_kernel(
    const float* __restrict__ M1, const float* __restrict__ M2,
    int* __restrict__ h1, float* __restrict__ s1,
    int* __restrict__ h2, float* __restrict__ s2)
{
    const int row = blockIdx.x;
    const float* M = blockIdx.y ? M2 : M1;
    int*   h = blockIdx.y ? h2 : h1;
    float* s = blockIdx.y ? s2 : s1;
    const float* mrow = M + (size_t)row * PROJ;

    for (int i = threadIdx.x * 4; i < PROJ; i += 256 * 4) {
        float4 v = *(const float4*)(mrow + i);
        if (v.x != 0.0f) { h[row] = i + 0; s[row] = v.x; }
        if (v.y != 0.0f) { h[row] = i + 1; s[row] = v.y; }
        if (v.z != 0.0f) { h[row] = i + 2; s[row] = v.z; }
        if (v.w != 0.0f) { h[row] = i + 3; s[row] = v.w; }
    }
}

// ---------------------------------------------------------------------------
// Kernel 2: combo — blocks 0..223 run prep (r0-verbatim body); blocks
// 224..239 build the bin-sorted u32 CSR for one segment each:
//   pass1 LDS histogram -> in-block scan (thread-serial over 32 bins +
//   Hillis-Steele over 256 totals) -> cnt[] becomes running base ->
//   pass2 rank via ds_add_rtn, write csr32 = bin<<15 | sign<<14 | rc.
// Replaces r7's scan_kernel (320+ barriers) and place_kernel entirely.
// ---------------------------------------------------------------------------
__global__ __launch_bounds__(256) void combo_kernel(
    const float* __restrict__ x,
    unsigned short* __restrict__ XThi, unsigned short* __restrict__ XTlo,
    const int* __restrict__ h1, const float* __restrict__ s1,
    const int* __restrict__ h2, const float* __restrict__ s2,
    unsigned* __restrict__ csr)
{
    __shared__ __align__(16) char smem[32 * 513 * 4];   // union: prep xt / csr cnt+sc
    const int tid = threadIdx.x;

    if (blockIdx.x < 224) {
        // ---- prep: split fp32 x into bf16 hi/lo, fragment order (r0) ----
        float (*xt)[513] = (float(*)[513])smem;
        const int ks = blockIdx.x % NSLAB;
        const int bt = blockIdx.x / NSLAB;        // 0..31
        const float* xb = x + (size_t)bt * HWPOS * CDIM;
        const int k0 = ks * 32;
#pragma unroll
        for (int i = 0; i < 16; ++i) {
            const int idx = i * 1024 + tid * 4;
            const int kr  = idx >> 9;
            const int c   = idx & 511;
            float4 v = make_float4(0.f, 0.f, 0.f, 0.f);
            if (k0 + kr < HWPOS) v = *(const float4*)(xb + (size_t)(k0 + kr) * CDIM + c);
            xt[kr][c+0] = v.x; xt[kr][c+1] = v.y; xt[kr][c+2] = v.z; xt[kr][c+3] = v.w;
        }
        __syncthreads();

        unsigned short* ohi = XThi + ((size_t)bt * NSLAB + ks) * 16384;
        unsigned short* olo = XTlo + ((size_t)bt * NSLAB + ks) * 16384;
#pragma unroll
        for (int i = 0; i < 8; ++i) {
            const int ch   = i * 256 + tid;
            const int c16  = ch & 15;
            const int quad = (ch >> 4) & 3;
            const int cgrp = ch >> 6;
            const int c    = cgrp * 16 + c16;
            short8 vh, vl;
#pragma unroll
            for (int j = 0; j < 8; ++j) {
                float f = xt[quad * 8 + j][c];
                unsigned short h = f2bf(f);
                vh[j] = (short)h;
                vl[j] = (short)f2bf(f - bf2f(h));
            }
            *(short8*)(ohi + ch * 8) = vh;
            *(short8*)(olo + ch * 8) = vl;
        }
    } else {
        // ---- buildcsr for segment seg ----
        unsigned* cnt = (unsigned*)smem;              // 8192 u32
        unsigned* sc  = (unsigned*)(smem + 32768);    // 256 u32
        const int seg = blockIdx.x - 224;

        for (int i = tid; i < PROJ; i += 256) cnt[i] = 0u;
        __syncthreads();
#pragma unroll
        for (int k = 0; k < 64; ++k) {                // pass 1: histogram
            const int e = k * 256 + tid;
            int bin, sg;
            seg_entry(seg, e, h1, s1, h2, s2, bin, sg);
            atomicAdd(&cnt[bin], 1u);
        }
        __syncthreads();

        unsigned c[32]; unsigned tot = 0;             // thread owns bins [tid*32, +32)
#pragma unroll
        for (int i = 0; i < 32; ++i) { c[i] = cnt[tid * 32 + i]; tot += c[i]; }
        sc[tid] = tot;
        __syncthreads();
        for (int off = 1; off < 256; off <<= 1) {     // Hillis-Steele inclusive
            unsigned v = (tid >= off) ? sc[tid - off] : 0u;
            __syncthreads();
            sc[tid] += v;
            __syncthreads();
        }
        unsigned base = sc[tid] - tot;                // exclusive prefix
#pragma unroll
        for (int i = 0; i < 32; ++i) { unsigned t = c[i]; cnt[tid * 32 + i] = base; base += t; }
        __syncthreads();

        unsigned* cs = csr + (size_t)seg * 16384;
#pragma unroll
        for (int k = 0; k < 64; ++k) {                // pass 2: place
            const int e = k * 256 + tid;
            int bin, sg;
            seg_entry(seg, e, h1, s1, h2, s2, bin, sg);
            const unsigned pos = atomicAdd(&cnt[bin], 1u);
            cs[pos] = ((unsigned)bin << 15) | ((unsigned)sg << 14) | (unsigned)e;
        }
    }
}

// ---------------------------------------------------------------------------
// Kernel 3: Gram (r4/r7-VERBATIM double-buffered staging + MFMA + tile-store)
// + POSITION-REGULAR segmented gather. Each thread owns CSR positions
// [tid*64, tid*64+64): 16 coalesced uint4 loads, 64 independent ds_reads,
// in-register run-reduce by bin. Interior runs -> plain store to this WG's
// private (pre-zeroed in-kernel) page; first/last runs (thread-boundary
// bins) -> unsafeAtomicAdd (<=2/thread). No dependent-length loops, no LDS
// atomics. LDS 64 KB -> 2 WGs/CU.
// ---------------------------------------------------------------------------
__global__ __launch_bounds__(256) void gramgather_kernel(
    const unsigned short* __restrict__ XThi, const unsigned short* __restrict__ XTlo,
    const unsigned* __restrict__ csr, float* __restrict__ pbins)
{
    const int id  = blockIdx.x;                   // 0..511
    const int sub = id >> 3;                      // 0..63
    const int tp  = sub & 15;                     // segment 0..15
    const int bat = (id & 7) + 8 * (sub >> 4);    // XCD swizzle
    const int bi = (int)((BI_PACK >> (tp * 4)) & 15);
    const int bj = (int)((BJ_PACK >> (tp * 4)) & 15);

    const int tid  = threadIdx.x;
    const int w    = tid >> 6;
    const int lane = tid & 63;
    const int rowq = w >> 1, colq = w & 1;

    __shared__ __align__(16) unsigned short Sbuf[2][4][4096]; // 64 KB dbuf -> tile

    const int tile = (w < 2) ? bi : bj;
    const unsigned short* srcbase = ((w & 1) ? XTlo : XThi)
                                  + (size_t)bat * NSLAB * 16384 + (size_t)tile * 4096;

    // issue async prefetch of slab 0 (r4 verbatim)
    {
        const unsigned short* src = srcbase;
        unsigned short* dst = &Sbuf[0][w][0];
#pragma unroll
        for (int i = 0; i < 8; ++i)
            __builtin_amdgcn_global_load_lds(
                (const __attribute__((address_space(1))) void*)(src + i * 512 + lane * 8),
                (__attribute__((address_space(3))) void*)(dst + i * 512), 16, 0, 0);
    }

    // zero this WG's private page while slab 0 is in flight (drained by the
    // issuing wave's own vmcnt at its next __syncthreads -> all zeros done
    // before any wave passes the post-MFMA barriers)
    float* page = pbins + ((size_t)bat * NSEG + tp) * PROJ;
    for (int i = tid * 4; i < PROJ; i += 1024)
        *(float4*)(page + i) = make_float4(0.f, 0.f, 0.f, 0.f);

    f32x4 acc[16];
#pragma unroll
    for (int i = 0; i < 16; ++i) { acc[i][0]=0.f; acc[i][1]=0.f; acc[i][2]=0.f; acc[i][3]=0.f; }

    for (int ks = 0; ks < NSLAB; ++ks) {
        __syncthreads();                 // drains vmcnt -> slab ks resident
        const int buf = ks & 1;

        if (ks + 1 < NSLAB) {            // prefetch next slab into other buffer
            const unsigned short* src = srcbase + (size_t)(ks + 1) * 16384;
            unsigned short* dst = &Sbuf[buf ^ 1][w][0];
#pragma unroll
            for (int i = 0; i < 8; ++i)
                __builtin_amdgcn_global_load_lds(
                    (const __attribute__((address_space(1))) void*)(src + i * 512 + lane * 8),
                    (__attribute__((address_space(3))) void*)(dst + i * 512), 16, 0, 0);
        }

        short8 ah[4], al[4], bh4[4], bl[4];
#pragma unroll
        for (int t = 0; t < 4; ++t) {
            ah[t]  = *(const short8*)&Sbuf[buf][0][(rowq * 4 + t) * 512 + lane * 8];
            al[t]  = *(const short8*)&Sbuf[buf][1][(rowq * 4 + t) * 512 + lane * 8];
            bh4[t] = *(const short8*)&Sbuf[buf][2][(colq * 4 + t) * 512 + lane * 8];
            bl[t]  = *(const short8*)&Sbuf[buf][3][(colq * 4 + t) * 512 + lane * 8];
        }
#pragma unroll
        for (int mt = 0; mt < 4; ++mt)
#pragma unroll
            for (int nt = 0; nt < 4; ++nt) {
                const int idx = mt * 4 + nt;
                acc[idx] = __builtin_amdgcn_mfma_f32_16x16x32_bf16(ah[mt], bh4[nt], acc[idx], 0, 0, 0);
                acc[idx] = __builtin_amdgcn_mfma_f32_16x16x32_bf16(ah[mt], bl[nt],  acc[idx], 0, 0, 0);
                acc[idx] = __builtin_amdgcn_mfma_f32_16x16x32_bf16(al[mt], bh4[nt], acc[idx], 0, 0, 0);
            }
    }

    __syncthreads();                     // all waves done with Sbuf -> reuse as tile
    float* tileL = (float*)Sbuf;         // 16384 f32 = 64 KB exactly
    const int quad = lane >> 4;
#pragma unroll
    for (int mt = 0; mt < 4; ++mt)
#pragma unroll
        for (int reg = 0; reg < 4; ++reg) {
            const int rl = rowq * 64 + mt * 16 + quad * 4 + reg;
#pragma unroll
            for (int nt = 0; nt < 4; ++nt) {
                const int cl = colq * 64 + nt * 16 + (lane & 15);
                tileL[rl * 128 + cl] = acc[mt * 4 + nt][reg];
            }
        }
    __syncthreads();                     // tile visible; page zeros drained

    // ---- position-regular segmented gather ----
    const uint4* ce = (const uint4*)(csr + (size_t)tp * 16384 + (size_t)tid * 64);
    uint4 E[16];
#pragma unroll
    for (int i = 0; i < 16; ++i) E[i] = ce[i];

    float a = 0.f;
    unsigned cur = E[0].x >> 15;
    bool first = true;
#pragma unroll
    for (int i = 0; i < 16; ++i) {
#pragma unroll
        for (int j = 0; j < 4; ++j) {
            const unsigned ent = (j == 0) ? E[i].x : (j == 1) ? E[i].y
                               : (j == 2) ? E[i].z : E[i].w;
            const unsigned b = ent >> 15;
            float v = tileL[ent & 0x3FFF];
            v = (ent & 0x4000u) ? -v : v;
            if (b != cur) {
                if (first) { unsafeAtomicAdd(&page[cur], a); first = false; }
                else       { page[cur] = a; }
                cur = b; a = v;
            } else {
                a += v;
            }
        }
    }
    unsafeAtomicAdd(&page[cur], a);      // final run always atomic
}

// ---------------------------------------------------------------------------
// Kernel 4: finalize — sum 16 pages, signed sqrt, block-reduce norm, scale.
// (r7 verbatim, passed)
// ---------------------------------------------------------------------------
__global__ __launch_bounds__(512) void finalize_kernel(
    const float* __restrict__ pbins, float* __restrict__ out)
{
    const int bat = blockIdx.x;
    const int tid = threadIdx.x;
    const float* pb = pbins + (size_t)bat * NSEG * PROJ;

    float4 y0, y1, y2, y3;
    float local = 0.f;

#pragma unroll
    for (int c = 0; c < 4; ++c) {
        const int base = c * 2048 + tid * 4;
        float4 a = make_float4(0.f, 0.f, 0.f, 0.f);
#pragma unroll
        for (int t = 0; t < NSEG; ++t) {
            float4 p = *(const float4*)(pb + (size_t)t * PROJ + base);
            a.x += p.x; a.y += p.y; a.z += p.z; a.w += p.w;
        }
        local += fabsf(a.x) + fabsf(a.y) + fabsf(a.z) + fabsf(a.w);
        float4 sv;
        sv.x = (a.x >= 0.f) ? sqrtf(a.x) : -sqrtf(-a.x);
        sv.y = (a.y >= 0.f) ? sqrtf(a.y) : -sqrtf(-a.y);
        sv.z = (a.z >= 0.f) ? sqrtf(a.z) : -sqrtf(-a.z);
        sv.w = (a.w >= 0.f) ? sqrtf(a.w) : -sqrtf(-a.w);
        if (c == 0) y0 = sv; else if (c == 1) y1 = sv; else if (c == 2) y2 = sv; else y3 = sv;
    }

#pragma unroll
    for (int off = 32; off > 0; off >>= 1) local += __shfl_down(local, off, 64);

    __shared__ float wred[8];
    __shared__ float sinv;
    if ((tid & 63) == 0) wred[tid >> 6] = local;
    __syncthreads();
    if (tid == 0) {
        float t = 0.f;
#pragma unroll
        for (int i = 0; i < 8; ++i) t += wred[i];
        sinv = rsqrtf(fmaxf(t, 1e-10f));
    }
    __syncthreads();
    const float inv = sinv;

    float* ob = out + (size_t)bat * PROJ;
#pragma unroll
    for (int c = 0; c < 4; ++c) {
        float4 sv = (c == 0) ? y0 : (c == 1) ? y1 : (c == 2) ? y2 : y3;
        sv.x *= inv; sv.y *= inv; sv.z *= inv; sv.w *= inv;
        *(float4*)(ob + c * 2048 + tid * 4) = sv;
    }
}

// ---------------------------------------------------------------------------
extern "C" void kernel_launch(void* const* d_in, const int* in_sizes, int n_in,
                              void* d_out, int out_size, void* d_ws, size_t ws_size,
                              hipStream_t stream)
{
    const float* x  = (const float*)d_in[0];   // [32,14,14,512]
    const float* M1 = (const float*)d_in[1];   // [512,8192]
    const float* M2 = (const float*)d_in[2];   // [512,8192]
    float* out = (float*)d_out;                // [32,8192]

    char* ws = (char*)d_ws;
    int*            h1    = (int*)   (ws + 0);
    float*          s1    = (float*) (ws + 2048);
    int*            h2    = (int*)   (ws + 4096);
    float*          s2    = (float*) (ws + 6144);
    unsigned*       csr   = (unsigned*)(ws + 16384);            // 1,048,576 B
    unsigned short* XThi  = (unsigned short*)(ws + 1064960);    // 7,340,032 B
    unsigned short* XTlo  = (unsigned short*)(ws + 8404992);    // 7,340,032 B
    float*          pbins = (float*) (ws + 15745024);           // 16,777,216 B
    // total ws use 32,522,240 B = 31.02 MiB (== round-7 proven footprint)

    extract_kernel<<<dim3(512, 2), 256, 0, stream>>>(M1, M2, h1, s1, h2, s2);
    combo_kernel<<<240, 256, 0, stream>>>(x, XThi, XTlo, h1, s1, h2, s2, csr);
    gramgather_kernel<<<NSEG * NBATCH, 256, 0, stream>>>(XThi, XTlo, csr, pbins);
    finalize_kernel<<<NBATCH, 512, 0, stream>>>(pbins, out);
}

// Round 9
// 162.226 us; speedup vs baseline: 1.2537x; 1.1073x over previous
//
#include <hip/hip_runtime.h>
#include <math.h>

#define PROJ 8192
#define CDIM 512
#define HWPOS 196
#define NBATCH 32
#define NSLAB 7             // K padded 196 -> 224 = 7 slabs of 32
#define NSEG 16             // 4 diag + 6 pairs x {fwd, mirror}; 16384 entries each

typedef __attribute__((ext_vector_type(8))) short   short8;
typedef __attribute__((ext_vector_type(4))) float   f32x4;

__device__ __forceinline__ unsigned short f2bf(float f) {
    unsigned u = __float_as_uint(f);
    u += 0x7fff + ((u >> 16) & 1);          // round-to-nearest-even
    return (unsigned short)(u >> 16);
}
__device__ __forceinline__ float bf2f(unsigned short h) {
    return __uint_as_float(((unsigned)h) << 16);
}

// Native LDS atomics via inline asm on explicit addrspace(3) pointers.
// r8 lesson (combo 149 us, occupancy 0.049% = ONE stalled block): atomicAdd
// through a generic pointer cast from a char-union LDS array takes the slow
// safe path (~2800 cy/wave-op measured: 128 ops x 2800 = 149 us exactly).
// ds_add_u32 / ds_add_rtn_u32 are single-issue (~235 cy/wave-op, the r6
// scatter rate). The rtn variant fuses its lgkmcnt(0) so the result is ready
// before any consumer (rule-18-safe: producer and wait in one asm stmt).
__device__ __forceinline__ void lds_uadd(unsigned* p, unsigned v) {
    __attribute__((address_space(3))) unsigned* lp =
        (__attribute__((address_space(3))) unsigned*)p;
    asm volatile("ds_add_u32 %0, %1" : : "v"(lp), "v"(v) : "memory");
}
__device__ __forceinline__ unsigned lds_uadd_rtn(unsigned* p, unsigned v) {
    __attribute__((address_space(3))) unsigned* lp =
        (__attribute__((address_space(3))) unsigned*)p;
    unsigned r;
    asm volatile("ds_add_rtn_u32 %0, %1, %2\n\ts_waitcnt lgkmcnt(0)"
                 : "=v"(r) : "v"(lp), "v"(v) : "memory");
    return r;
}

// Segment decode (r4/r7/r8-verified packs). seg 0..3: diag (t,t) fwd; 4..9:
// pairs (0,1)(0,2)(0,3)(1,2)(1,3)(2,3) fwd; 10..15: same pairs, mirror.
#define BI_PACK 0x2110002110003210ULL
#define BJ_PACK 0x3323213323213210ULL

// Entry e in [0,16384): r=e>>7, c=e&127 of tile (bi,bj). (r7/r8-verbatim)
__device__ __forceinline__ void seg_entry(int seg, int e,
    const int* __restrict__ h1, const float* __restrict__ s1,
    const int* __restrict__ h2, const float* __restrict__ s2,
    int& bin, int& sg)
{
    const int bi = (int)((BI_PACK >> (seg * 4)) & 15);
    const int bj = (int)((BJ_PACK >> (seg * 4)) & 15);
    const int r = e >> 7, c = e & 127;
    int gi, gj;
    if (seg < 10) { gi = bi * 128 + r; gj = bj * 128 + c; }
    else          { gi = bj * 128 + c; gj = bi * 128 + r; }
    bin = (h1[gi] + h2[gj]) & (PROJ - 1);
    sg  = (int)((__float_as_uint(s1[gi]) ^ __float_as_uint(s2[gj])) >> 31); // s=+-1
}

// ---------------------------------------------------------------------------
// Kernel 1: extract (h, s) from the dense sketch matrices + zero norm accum.
// (r0 verbatim)
// ---------------------------------------------------------------------------
__global__ __launch_bounds__(256) void extract_kernel(
    const float* __restrict__ M1, const float* __restrict__ M2,
    int* __restrict__ h1, float* __restrict__ s1,
    int* __restrict__ h2, float* __restrict__ s2,
    float* __restrict__ norm)
{
    const int row = blockIdx.x;
    const float* M = blockIdx.y ? M2 : M1;
    int*   h = blockIdx.y ? h2 : h1;
    float* s = blockIdx.y ? s2 : s1;
    const float* mrow = M + (size_t)row * PROJ;

    if (blockIdx.x == 0 && blockIdx.y == 0 && threadIdx.x < NBATCH)
        norm[threadIdx.x] = 0.0f;

    for (int i = threadIdx.x * 4; i < PROJ; i += 256 * 4) {
        float4 v = *(const float4*)(mrow + i);
        if (v.x != 0.0f) { h[row] = i + 0; s[row] = v.x; }
        if (v.y != 0.0f) { h[row] = i + 1; s[row] = v.y; }
        if (v.z != 0.0f) { h[row] = i + 2; s[row] = v.z; }
        if (v.w != 0.0f) { h[row] = i + 3; s[row] = v.w; }
    }
}

// ---------------------------------------------------------------------------
// Kernel 2: combo — blocks 0..223 run prep (r0-verbatim body); blocks
// 224..239 build the bin-sorted u32 CSR for one segment each (hist ->
// in-block scan -> place). Build LDS arrays are DIRECT __shared__ typed
// arrays (no generic-pointer casts) and both atomics are native ds ops.
// ---------------------------------------------------------------------------
__global__ __launch_bounds__(256) void combo_kernel(
    const float* __restrict__ x,
    unsigned short* __restrict__ XThi, unsigned short* __restrict__ XTlo,
    const int* __restrict__ h1, const float* __restrict__ s1,
    const int* __restrict__ h2, const float* __restrict__ s2,
    unsigned* __restrict__ csr)
{
    __shared__ float    xt[32][513];          // prep transpose buffer (65.7 KB)
    __shared__ unsigned cnt[PROJ];            // build histogram/bases (32 KB)
    __shared__ unsigned sc[256];
    const int tid = threadIdx.x;

    if (blockIdx.x < 224) {
        // ---- prep: split fp32 x into bf16 hi/lo, fragment order (r0) ----
        const int ks = blockIdx.x % NSLAB;
        const int bt = blockIdx.x / NSLAB;        // 0..31
        const float* xb = x + (size_t)bt * HWPOS * CDIM;
        const int k0 = ks * 32;
#pragma unroll
        for (int i = 0; i < 16; ++i) {
            const int idx = i * 1024 + tid * 4;
            const int kr  = idx >> 9;
            const int c   = idx & 511;
            float4 v = make_float4(0.f, 0.f, 0.f, 0.f);
            if (k0 + kr < HWPOS) v = *(const float4*)(xb + (size_t)(k0 + kr) * CDIM + c);
            xt[kr][c+0] = v.x; xt[kr][c+1] = v.y; xt[kr][c+2] = v.z; xt[kr][c+3] = v.w;
        }
        __syncthreads();

        unsigned short* ohi = XThi + ((size_t)bt * NSLAB + ks) * 16384;
        unsigned short* olo = XTlo + ((size_t)bt * NSLAB + ks) * 16384;
#pragma unroll
        for (int i = 0; i < 8; ++i) {
            const int ch   = i * 256 + tid;
            const int c16  = ch & 15;
            const int quad = (ch >> 4) & 3;
            const int cgrp = ch >> 6;
            const int c    = cgrp * 16 + c16;
            short8 vh, vl;
#pragma unroll
            for (int j = 0; j < 8; ++j) {
                float f = xt[quad * 8 + j][c];
                unsigned short h = f2bf(f);
                vh[j] = (short)h;
                vl[j] = (short)f2bf(f - bf2f(h));
            }
            *(short8*)(ohi + ch * 8) = vh;
            *(short8*)(olo + ch * 8) = vl;
        }
    } else {
        // ---- buildcsr for segment seg (native ds atomics) ----
        const int seg = blockIdx.x - 224;

        for (int i = tid; i < PROJ; i += 256) cnt[i] = 0u;
        __syncthreads();
#pragma unroll 8
        for (int k = 0; k < 64; ++k) {                // pass 1: histogram
            const int e = k * 256 + tid;
            int bin, sg;
            seg_entry(seg, e, h1, s1, h2, s2, bin, sg);
            lds_uadd(&cnt[bin], 1u);
        }
        __syncthreads();                              // lgkm drain covers ds_adds

        unsigned c[32]; unsigned tot = 0;             // thread owns bins [tid*32,+32)
#pragma unroll
        for (int i = 0; i < 32; ++i) { c[i] = cnt[tid * 32 + i]; tot += c[i]; }
        sc[tid] = tot;
        __syncthreads();
        for (int off = 1; off < 256; off <<= 1) {     // Hillis-Steele inclusive
            unsigned v = (tid >= off) ? sc[tid - off] : 0u;
            __syncthreads();
            sc[tid] += v;
            __syncthreads();
        }
        unsigned base = sc[tid] - tot;                // exclusive prefix
#pragma unroll
        for (int i = 0; i < 32; ++i) { unsigned t = c[i]; cnt[tid * 32 + i] = base; base += t; }
        __syncthreads();

        unsigned* cs = csr + (size_t)seg * 16384;
#pragma unroll 8
        for (int k = 0; k < 64; ++k) {                // pass 2: place
            const int e = k * 256 + tid;
            int bin, sg;
            seg_entry(seg, e, h1, s1, h2, s2, bin, sg);
            const unsigned pos = lds_uadd_rtn(&cnt[bin], 1u);
            cs[pos] = ((unsigned)bin << 15) | ((unsigned)sg << 14) | (unsigned)e;
        }
    }
}

// ---------------------------------------------------------------------------
// Kernel 3: Gram (r8 VERBATIM, passed) — double-buffered staging + MFMA +
// tile-store + position-regular segmented gather.
// ---------------------------------------------------------------------------
__global__ __launch_bounds__(256) void gramgather_kernel(
    const unsigned short* __restrict__ XThi, const unsigned short* __restrict__ XTlo,
    const unsigned* __restrict__ csr, float* __restrict__ pbins)
{
    const int id  = blockIdx.x;                   // 0..511
    const int sub = id >> 3;                      // 0..63
    const int tp  = sub & 15;                     // segment 0..15
    const int bat = (id & 7) + 8 * (sub >> 4);    // XCD swizzle
    const int bi = (int)((BI_PACK >> (tp * 4)) & 15);
    const int bj = (int)((BJ_PACK >> (tp * 4)) & 15);

    const int tid  = threadIdx.x;
    const int w    = tid >> 6;
    const int lane = tid & 63;
    const int rowq = w >> 1, colq = w & 1;

    __shared__ __align__(16) unsigned short Sbuf[2][4][4096]; // 64 KB dbuf -> tile

    const int tile = (w < 2) ? bi : bj;
    const unsigned short* srcbase = ((w & 1) ? XTlo : XThi)
                                  + (size_t)bat * NSLAB * 16384 + (size_t)tile * 4096;

    // issue async prefetch of slab 0 (r4 verbatim)
    {
        const unsigned short* src = srcbase;
        unsigned short* dst = &Sbuf[0][w][0];
#pragma unroll
        for (int i = 0; i < 8; ++i)
            __builtin_amdgcn_global_load_lds(
                (const __attribute__((address_space(1))) void*)(src + i * 512 + lane * 8),
                (__attribute__((address_space(3))) void*)(dst + i * 512), 16, 0, 0);
    }

    // zero this WG's private page while slab 0 is in flight
    float* page = pbins + ((size_t)bat * NSEG + tp) * PROJ;
    for (int i = tid * 4; i < PROJ; i += 1024)
        *(float4*)(page + i) = make_float4(0.f, 0.f, 0.f, 0.f);

    f32x4 acc[16];
#pragma unroll
    for (int i = 0; i < 16; ++i) { acc[i][0]=0.f; acc[i][1]=0.f; acc[i][2]=0.f; acc[i][3]=0.f; }

    for (int ks = 0; ks < NSLAB; ++ks) {
        __syncthreads();                 // drains vmcnt -> slab ks resident
        const int buf = ks & 1;

        if (ks + 1 < NSLAB) {            // prefetch next slab into other buffer
            const unsigned short* src = srcbase + (size_t)(ks + 1) * 16384;
            unsigned short* dst = &Sbuf[buf ^ 1][w][0];
#pragma unroll
            for (int i = 0; i < 8; ++i)
                __builtin_amdgcn_global_load_lds(
                    (const __attribute__((address_space(1))) void*)(src + i * 512 + lane * 8),
                    (__attribute__((address_space(3))) void*)(dst + i * 512), 16, 0, 0);
        }

        short8 ah[4], al[4], bh4[4], bl[4];
#pragma unroll
        for (int t = 0; t < 4; ++t) {
            ah[t]  = *(const short8*)&Sbuf[buf][0][(rowq * 4 + t) * 512 + lane * 8];
            al[t]  = *(const short8*)&Sbuf[buf][1][(rowq * 4 + t) * 512 + lane * 8];
            bh4[t] = *(const short8*)&Sbuf[buf][2][(colq * 4 + t) * 512 + lane * 8];
            bl[t]  = *(const short8*)&Sbuf[buf][3][(colq * 4 + t) * 512 + lane * 8];
        }
#pragma unroll
        for (int mt = 0; mt < 4; ++mt)
#pragma unroll
            for (int nt = 0; nt < 4; ++nt) {
                const int idx = mt * 4 + nt;
                acc[idx] = __builtin_amdgcn_mfma_f32_16x16x32_bf16(ah[mt], bh4[nt], acc[idx], 0, 0, 0);
                acc[idx] = __builtin_amdgcn_mfma_f32_16x16x32_bf16(ah[mt], bl[nt],  acc[idx], 0, 0, 0);
                acc[idx] = __builtin_amdgcn_mfma_f32_16x16x32_bf16(al[mt], bh4[nt], acc[idx], 0, 0, 0);
            }
    }

    __syncthreads();                     // all waves done with Sbuf -> reuse as tile
    float* tileL = (float*)Sbuf;         // 16384 f32 = 64 KB exactly
    const int quad = lane >> 4;
#pragma unroll
    for (int mt = 0; mt < 4; ++mt)
#pragma unroll
        for (int reg = 0; reg < 4; ++reg) {
            const int rl = rowq * 64 + mt * 16 + quad * 4 + reg;
#pragma unroll
            for (int nt = 0; nt < 4; ++nt) {
                const int cl = colq * 64 + nt * 16 + (lane & 15);
                tileL[rl * 128 + cl] = acc[mt * 4 + nt][reg];
            }
        }
    __syncthreads();                     // tile visible; page zeros drained

    // ---- position-regular segmented gather ----
    const uint4* ce = (const uint4*)(csr + (size_t)tp * 16384 + (size_t)tid * 64);
    uint4 E[16];
#pragma unroll
    for (int i = 0; i < 16; ++i) E[i] = ce[i];

    float a = 0.f;
    unsigned cur = E[0].x >> 15;
    bool first = true;
#pragma unroll
    for (int i = 0; i < 16; ++i) {
#pragma unroll
        for (int j = 0; j < 4; ++j) {
            const unsigned ent = (j == 0) ? E[i].x : (j == 1) ? E[i].y
                               : (j == 2) ? E[i].z : E[i].w;
            const unsigned b = ent >> 15;
            float v = tileL[ent & 0x3FFF];
            v = (ent & 0x4000u) ? -v : v;
            if (b != cur) {
                if (first) { unsafeAtomicAdd(&page[cur], a); first = false; }
                else       { page[cur] = a; }
                cur = b; a = v;
            } else {
                a += v;
            }
        }
    }
    unsafeAtomicAdd(&page[cur], a);      // final run always atomic
}

// ---------------------------------------------------------------------------
// Kernel 4: reduce NSEG partials per bin, signed sqrt, emit unnormalized y,
// accumulate per-batch sum |v| (== sum y^2). Grid (8, 32). (r0 verbatim)
// ---------------------------------------------------------------------------
__global__ __launch_bounds__(256) void reduce_kernel(
    const float* __restrict__ pbins, float* __restrict__ out,
    float* __restrict__ norm)
{
    const int chunk = blockIdx.x;
    const int bat   = blockIdx.y;
    const int tid   = threadIdx.x;
    const int base  = chunk * 1024 + tid * 4;

    const float* pb = pbins + (size_t)bat * NSEG * PROJ;
    float4 v = make_float4(0.f, 0.f, 0.f, 0.f);
#pragma unroll
    for (int t = 0; t < NSEG; ++t) {
        float4 p = *(const float4*)(pb + (size_t)t * PROJ + base);
        v.x += p.x; v.y += p.y; v.z += p.z; v.w += p.w;
    }

    float4 sv;
    sv.x = (v.x >= 0.f) ? sqrtf(v.x) : -sqrtf(-v.x);
    sv.y = (v.y >= 0.f) ? sqrtf(v.y) : -sqrtf(-v.y);
    sv.z = (v.z >= 0.f) ? sqrtf(v.z) : -sqrtf(-v.z);
    sv.w = (v.w >= 0.f) ? sqrtf(v.w) : -sqrtf(-v.w);
    *(float4*)(out + (size_t)bat * PROJ + base) = sv;

    float local = fabsf(v.x) + fabsf(v.y) + fabsf(v.z) + fabsf(v.w);
#pragma unroll
    for (int off = 32; off > 0; off >>= 1) local += __shfl_down(local, off, 64);

    __shared__ float wred[4];
    if ((tid & 63) == 0) wred[tid >> 6] = local;
    __syncthreads();
    if (tid == 0)
        unsafeAtomicAdd(&norm[bat], wred[0] + wred[1] + wred[2] + wred[3]);
}

// ---------------------------------------------------------------------------
// Kernel 5: scale by rsqrt(norm). Grid (8, 32). (r0 verbatim)
// ---------------------------------------------------------------------------
__global__ __launch_bounds__(256) void normalize_kernel(
    float* __restrict__ out, const float* __restrict__ norm)
{
    const int bat = blockIdx.y;
    const int idx = blockIdx.x * 1024 + threadIdx.x * 4;
    const float inv = rsqrtf(fmaxf(norm[bat], 1e-10f));
    float4* p = (float4*)(out + (size_t)bat * PROJ + idx);
    float4 v = *p;
    v.x *= inv; v.y *= inv; v.z *= inv; v.w *= inv;
    *p = v;
}

// ---------------------------------------------------------------------------
extern "C" void kernel_launch(void* const* d_in, const int* in_sizes, int n_in,
                              void* d_out, int out_size, void* d_ws, size_t ws_size,
                              hipStream_t stream)
{
    const float* x  = (const float*)d_in[0];   // [32,14,14,512]
    const float* M1 = (const float*)d_in[1];   // [512,8192]
    const float* M2 = (const float*)d_in[2];   // [512,8192]
    float* out = (float*)d_out;                // [32,8192]

    char* ws = (char*)d_ws;
    int*            h1    = (int*)   (ws + 0);
    float*          s1    = (float*) (ws + 2048);
    int*            h2    = (int*)   (ws + 4096);
    float*          s2    = (float*) (ws + 6144);
    float*          norm  = (float*) (ws + 8192);
    unsigned*       csr   = (unsigned*)(ws + 16384);            // 1,048,576 B
    unsigned short* XThi  = (unsigned short*)(ws + 1064960);    // 7,340,032 B
    unsigned short* XTlo  = (unsigned short*)(ws + 8404992);    // 7,340,032 B
    float*          pbins = (float*) (ws + 15745024);           // 16,777,216 B
    // total ws use 32,522,240 B = 31.02 MiB (== round-7/8 proven footprint)

    extract_kernel<<<dim3(512, 2), 256, 0, stream>>>(M1, M2, h1, s1, h2, s2, norm);
    combo_kernel<<<240, 256, 0, stream>>>(x, XThi, XTlo, h1, s1, h2, s2, csr);
    gramgather_kernel<<<NSEG * NBATCH, 256, 0, stream>>>(XThi, XTlo, csr, pbins);
    reduce_kernel<<<dim3(8, NBATCH), 256, 0, stream>>>(pbins, out, norm);
    normalize_kernel<<<dim3(8, NBATCH), 256, 0, stream>>>(out, norm);
}